// Round 4
// baseline (95.373 us; speedup 1.0000x reference)
//
#include <hip/hip_runtime.h>

#define Hd 256
#define Ad 64
#define NPSd 48
#define Sd 64
#define Nd (Sd*NPSd)
#define GB 16    // agents per block in v_kernel
#define TILE 8   // j-rows per tile in attn_kernel
#define NT (NPSd/TILE)   // 6 tiles

// ---------------------------------------------------------------------------
// async global->LDS copy, 16B per lane: LDS dest = wave-uniform base + lane*16
__device__ __forceinline__ void gload16(const float* g, float* l) {
  __builtin_amdgcn_global_load_lds(
      (const __attribute__((address_space(1))) void*)g,
      (__attribute__((address_space(3))) void*)l, 16, 0, 0);
}

// ---------------------------------------------------------------------------
// Kernel A: combo weights.  Wc[h1][h] = sum_a W2[a][h1]*W1[a][h]
//           vb[h] = sum_a b2[a]*W1[a][h]
//           u[h1] = sum_a W2[a][h1]*b1[a]
//           cconst = b1.b2
__global__ __launch_bounds__(256) void combo_kernel(
    const float* __restrict__ W1_w, const float* __restrict__ W1_b,
    const float* __restrict__ W2_w, const float* __restrict__ W2_b,
    float* __restrict__ Wc, float* __restrict__ vb,
    float* __restrict__ u, float* __restrict__ cconst) {
  int h1 = blockIdx.x;
  int h  = threadIdx.x;
  float acc = 0.f;
#pragma unroll 8
  for (int a = 0; a < Ad; ++a)
    acc += W2_w[a*Hd + h1] * W1_w[a*Hd + h];
  Wc[h1*Hd + h] = acc;
  if (h1 == 0) {
    float uu = 0.f, vbb = 0.f;
    for (int a = 0; a < Ad; ++a) {
      uu  += W2_w[a*Hd + h] * W1_b[a];
      vbb += W2_b[a] * W1_w[a*Hd + h];
    }
    u[h]  = uu;
    vb[h] = vbb;
    if (h == 0) {
      float cc = 0.f;
      for (int a = 0; a < Ad; ++a) cc += W1_b[a] * W2_b[a];
      *cconst = cc;
    }
  }
}

// ---------------------------------------------------------------------------
// Kernel B: v[i][:] = t[i].Wc + vb ;  c[i] = t[i].u + cconst
__global__ __launch_bounds__(256) void v_kernel(
    const float* __restrict__ temporal,
    const float* __restrict__ Wc, const float* __restrict__ vb,
    const float* __restrict__ u, const float* __restrict__ cconst,
    float* __restrict__ v, float* __restrict__ c) {
  __shared__ float t_lds[GB*Hd];
  __shared__ float u_lds[Hd];
  __shared__ float vb_lds[Hd];
  int tid  = threadIdx.x;
  int base = blockIdx.x * GB;
  for (int k = tid; k < GB*Hd; k += 256)
    t_lds[k] = temporal[(size_t)base*Hd + k];
  u_lds[tid]  = u[tid];
  vb_lds[tid] = vb[tid];
  __syncthreads();

  float acc[GB];
#pragma unroll
  for (int g = 0; g < GB; ++g) acc[g] = 0.f;
  for (int h1 = 0; h1 < Hd; ++h1) {
    float wc = Wc[h1*Hd + tid];          // coalesced over tid
#pragma unroll
    for (int g = 0; g < GB; ++g)
      acc[g] += t_lds[g*Hd + h1] * wc;   // LDS broadcast
  }
#pragma unroll
  for (int g = 0; g < GB; ++g)
    v[(size_t)(base+g)*Hd + tid] = acc[g] + vb_lds[tid];

  int wave = tid >> 6, lane = tid & 63;
  float cc0 = *cconst;
  for (int gg = 0; gg < GB/4; ++gg) {
    int g = wave*(GB/4) + gg;
    float p = 0.f;
#pragma unroll
    for (int k = 0; k < Hd/64; ++k)
      p += t_lds[g*Hd + lane + k*64] * u_lds[lane + k*64];
#pragma unroll
    for (int off = 32; off > 0; off >>= 1)
      p += __shfl_down(p, off);
    if (lane == 0) c[base+g] = p + cc0;
  }
}

// ---------------------------------------------------------------------------
// Kernel C: fused score + masked (unstabilized) softmax + aggregation.
// One block per (scene,row). j-dim tiled 6x8, double-buffered LDS staged via
// global_load_lds; raw s_barrier + counted vmcnt so the next tile's loads
// stay in flight under compute. Online accumulation of den/out.
__global__ __launch_bounds__(256) void attn_kernel(
    const float* __restrict__ spatial,
    const int* __restrict__ ts_mask,
    const float* __restrict__ v, const float* __restrict__ c,
    float* __restrict__ out) {
  __shared__ float buf[2][TILE*Hd];   // 2 x 8 KB
  __shared__ int   msk[NPSd];

  int row = blockIdx.x;               // 0..N-1
  int s = row / NPSd, i = row - s*NPSd;
  int tid  = threadIdx.x;
  int wave = tid >> 6, lane = tid & 63;

  const float* rowbase = spatial + (size_t)row*NPSd*Hd;

  // stage tile 0: 8 chunks of 256 floats; each wave stages chunks wave, wave+4
#pragma unroll
  for (int chk = wave; chk < TILE*Hd/256; chk += 4)
    gload16(rowbase + chk*256 + lane*4, buf[0] + chk*256);

  if (tid < NPSd) msk[tid] = ts_mask[s*NPSd + tid];

  float4 vv = ((const float4*)(v + (size_t)row*Hd))[lane];
  float cr = c[row];

  __syncthreads();   // drains stage(0) (vmcnt+lgkmcnt), publishes msk

  float ne = 0.f;
#pragma unroll
  for (int j = 0; j < NPSd; ++j) ne += (msk[j] == 1) ? 1.f : 0.f;
  float scale = ne * 0.125f;          // ne / sqrt(A=64)
  bool rowv = (msk[i] == 1);

  float den = 0.f, o = 0.f;

  for (int t = 0; t < NT; ++t) {
    int cb = t & 1;
    if (t + 1 < NT) {
      const float* src = rowbase + (size_t)(t+1)*(TILE*Hd);
      float* dst = buf[cb^1];
      // each wave issues 2 gloads for tile t+1
#pragma unroll
      for (int chk = wave; chk < TILE*Hd/256; chk += 4)
        gload16(src + chk*256 + lane*4, dst + chk*256);
      // tile t's loads landed; tile t+1's 2 may remain outstanding
      asm volatile("s_waitcnt vmcnt(2)" ::: "memory");
    } else {
      asm volatile("s_waitcnt vmcnt(0)" ::: "memory");
    }
    __builtin_amdgcn_s_barrier();
    __builtin_amdgcn_sched_barrier(0);

#pragma unroll
    for (int jj = 0; jj < TILE; ++jj) {
      int j = t*TILE + jj;
      float4 a4 = ((const float4*)(buf[cb] + jj*Hd))[lane];
      float p = a4.x*vv.x + a4.y*vv.y + a4.z*vv.z + a4.w*vv.w;
      p += __shfl_xor(p, 1);
      p += __shfl_xor(p, 2);
      p += __shfl_xor(p, 4);
      p += __shfl_xor(p, 8);
      p += __shfl_xor(p, 16);
      p += __shfl_xor(p, 32);
      bool valid = rowv && (msk[j] == 1) && (j != i);
      float nj = valid ? __expf((p + cr) * scale) : 0.f;
      den += nj;
      o   += nj * buf[cb][jj*Hd + tid];   // stride-1 across lanes
    }

    __builtin_amdgcn_sched_barrier(0);
    asm volatile("s_waitcnt lgkmcnt(0)" ::: "memory");  // my LDS reads done
    __builtin_amdgcn_s_barrier();                        // safe to restage
  }

  out[(size_t)row*Hd + tid] = o * (den > 0.f ? 1.f/den : 0.f);
}

// ---------------------------------------------------------------------------
extern "C" void kernel_launch(void* const* d_in, const int* in_sizes, int n_in,
                              void* d_out, int out_size, void* d_ws, size_t ws_size,
                              hipStream_t stream) {
  const float* spatial  = (const float*)d_in[0];
  const float* temporal = (const float*)d_in[1];
  const float* W1_w     = (const float*)d_in[2];
  const float* W1_b     = (const float*)d_in[3];
  const float* W2_w     = (const float*)d_in[4];
  const float* W2_b     = (const float*)d_in[5];
  const int*   ts_mask  = (const int*)d_in[6];
  float* out = (float*)d_out;

  float* ws = (float*)d_ws;
  float* v      = ws;                  // N*H
  float* c      = v  + (size_t)Nd*Hd;  // N
  float* Wc     = c  + Nd;             // H*H
  float* vb     = Wc + Hd*Hd;          // H
  float* u      = vb + Hd;             // H
  float* cconst = u  + Hd;             // 1

  combo_kernel<<<Hd, Hd, 0, stream>>>(W1_w, W1_b, W2_w, W2_b, Wc, vb, u, cconst);
  v_kernel<<<Nd/GB, 256, 0, stream>>>(temporal, Wc, vb, u, cconst, v, c);
  attn_kernel<<<Nd, 256, 0, stream>>>(spatial, ts_mask, v, c, out);
}

// Round 5
// 68.185 us; speedup vs baseline: 1.3987x; 1.3987x over previous
//
#include <hip/hip_runtime.h>

#define Hd 256
#define Ad 64
#define NPSd 48
#define Sd 64
#define Nd (Sd*NPSd)
#define GB 16    // agents per block in v_kernel

// ---------------------------------------------------------------------------
// async global->LDS copy, 16B per lane: LDS dest = wave-uniform base + lane*16
__device__ __forceinline__ void gload16(const float* g, float* l) {
  __builtin_amdgcn_global_load_lds(
      (const __attribute__((address_space(1))) void*)g,
      (__attribute__((address_space(3))) void*)l, 16, 0, 0);
}

#define WAITV(n) asm volatile("s_waitcnt vmcnt(" #n ")" ::: "memory")

// ---------------------------------------------------------------------------
// Kernel A: combo weights.  Wc[h1][h] = sum_a W2[a][h1]*W1[a][h]
//           vb[h] = sum_a b2[a]*W1[a][h]
//           u[h1] = sum_a W2[a][h1]*b1[a]
//           cconst = b1.b2
__global__ __launch_bounds__(256) void combo_kernel(
    const float* __restrict__ W1_w, const float* __restrict__ W1_b,
    const float* __restrict__ W2_w, const float* __restrict__ W2_b,
    float* __restrict__ Wc, float* __restrict__ vb,
    float* __restrict__ u, float* __restrict__ cconst) {
  int h1 = blockIdx.x;
  int h  = threadIdx.x;
  float acc = 0.f;
#pragma unroll 8
  for (int a = 0; a < Ad; ++a)
    acc += W2_w[a*Hd + h1] * W1_w[a*Hd + h];
  Wc[h1*Hd + h] = acc;
  if (h1 == 0) {
    float uu = 0.f, vbb = 0.f;
    for (int a = 0; a < Ad; ++a) {
      uu  += W2_w[a*Hd + h] * W1_b[a];
      vbb += W2_b[a] * W1_w[a*Hd + h];
    }
    u[h]  = uu;
    vb[h] = vbb;
    if (h == 0) {
      float cc = 0.f;
      for (int a = 0; a < Ad; ++a) cc += W1_b[a] * W2_b[a];
      *cconst = cc;
    }
  }
}

// ---------------------------------------------------------------------------
// Kernel B: v[i][:] = t[i].Wc + vb ;  c[i] = t[i].u + cconst
__global__ __launch_bounds__(256) void v_kernel(
    const float* __restrict__ temporal,
    const float* __restrict__ Wc, const float* __restrict__ vb,
    const float* __restrict__ u, const float* __restrict__ cconst,
    float* __restrict__ v, float* __restrict__ c) {
  __shared__ float t_lds[GB*Hd];
  __shared__ float u_lds[Hd];
  __shared__ float vb_lds[Hd];
  int tid  = threadIdx.x;
  int base = blockIdx.x * GB;
  for (int k = tid; k < GB*Hd; k += 256)
    t_lds[k] = temporal[(size_t)base*Hd + k];
  u_lds[tid]  = u[tid];
  vb_lds[tid] = vb[tid];
  __syncthreads();

  float acc[GB];
#pragma unroll
  for (int g = 0; g < GB; ++g) acc[g] = 0.f;
  for (int h1 = 0; h1 < Hd; ++h1) {
    float wc = Wc[h1*Hd + tid];          // coalesced over tid
#pragma unroll
    for (int g = 0; g < GB; ++g)
      acc[g] += t_lds[g*Hd + h1] * wc;   // LDS broadcast
  }
#pragma unroll
  for (int g = 0; g < GB; ++g)
    v[(size_t)(base+g)*Hd + tid] = acc[g] + vb_lds[tid];

  int wave = tid >> 6, lane = tid & 63;
  float cc0 = *cconst;
  for (int gg = 0; gg < GB/4; ++gg) {
    int g = wave*(GB/4) + gg;
    float p = 0.f;
#pragma unroll
    for (int k = 0; k < Hd/64; ++k)
      p += t_lds[g*Hd + lane + k*64] * u_lds[lane + k*64];
#pragma unroll
    for (int off = 32; off > 0; off >>= 1)
      p += __shfl_down(p, off);
    if (lane == 0) c[base+g] = p + cc0;
  }
}

// ---------------------------------------------------------------------------
// Kernel C: fused score + masked (unstabilized) softmax + aggregation.
// One block per (scene,row). Single 48KB LDS buffer, write-once. Each wave
// stages rows {w, w+4} of each 8-row chunk via global_load_lds AND computes
// the scores for exactly those rows -> score phase needs NO barriers; each
// wave gates only on its own loads with counted vmcnt. All 12 loads are in
// flight from block start. One __syncthreads before aggregation.
__global__ __launch_bounds__(256) void attn_kernel(
    const float* __restrict__ spatial,
    const int* __restrict__ ts_mask,
    const float* __restrict__ v, const float* __restrict__ c,
    float* __restrict__ out) {
  __shared__ float sp[NPSd*Hd];   // 48 KB, row-major [48][256]
  __shared__ float num[NPSd];

  int row = blockIdx.x;               // 0..N-1
  int s = row / NPSd, i = row - s*NPSd;
  int tid  = threadIdx.x;
  int wave = tid >> 6, lane = tid & 63;

  const float* rowbase = spatial + (size_t)row*NPSd*Hd;

  // misc loads first (oldest in vmcnt queue), then consume before gloads
  int ml = lane < NPSd ? lane : NPSd-1;
  int mv = ts_mask[s*NPSd + ml];
  float4 vv = ((const float4*)(v + (size_t)row*Hd))[lane];
  float cr = c[row];

  unsigned long long mb = __ballot(mv == 1 && lane < NPSd);
  float ne = (float)__popcll(mb);
  float scale = ne * 0.125f;          // ne / sqrt(A=64)
  bool rowv = (mb >> (unsigned)i) & 1ULL;

  // issue ALL 12 gloads, chunk-major: wave w stages rows {w, w+4} per chunk
#pragma unroll
  for (int t = 0; t < 6; ++t) {
#pragma unroll
    for (int g = 0; g < 2; ++g) {
      int r = t*8 + wave + g*4;
      gload16(rowbase + r*256 + lane*4, sp + r*256);
    }
  }

  // score phase: chunk t gated by this wave's own loads only (no barriers)
#define SCORE_CHUNK(T)                                                      \
  {                                                                         \
    _Pragma("unroll")                                                       \
    for (int g = 0; g < 2; ++g) {                                           \
      int j = (T)*8 + wave + g*4;                                           \
      float4 a4 = ((const float4*)(sp + j*256))[lane];                      \
      float p = a4.x*vv.x + a4.y*vv.y + a4.z*vv.z + a4.w*vv.w;              \
      p += __shfl_xor(p, 1);                                                \
      p += __shfl_xor(p, 2);                                                \
      p += __shfl_xor(p, 4);                                                \
      p += __shfl_xor(p, 8);                                                \
      p += __shfl_xor(p, 16);                                               \
      p += __shfl_xor(p, 32);                                               \
      if (lane == 0) {                                                      \
        bool valid = rowv && ((mb >> (unsigned)j) & 1ULL) && (j != i);      \
        num[j] = valid ? __expf((p + cr) * scale) : 0.f;                    \
      }                                                                     \
    }                                                                       \
  }

  WAITV(10); SCORE_CHUNK(0);
  WAITV(8);  SCORE_CHUNK(1);
  WAITV(6);  SCORE_CHUNK(2);
  WAITV(4);  SCORE_CHUNK(3);
  WAITV(2);  SCORE_CHUNK(4);
  WAITV(0);  SCORE_CHUNK(5);
#undef SCORE_CHUNK

  __syncthreads();   // num + all rows visible to all waves

  float den = 0.f, o = 0.f;
#pragma unroll 8
  for (int j = 0; j < NPSd; ++j) {
    float nj = num[j];                 // LDS broadcast
    den += nj;
    o   += nj * sp[j*Hd + tid];        // stride-1 across lanes
  }
  out[(size_t)row*Hd + tid] = o * (den > 0.f ? 1.f/den : 0.f);
}

// ---------------------------------------------------------------------------
extern "C" void kernel_launch(void* const* d_in, const int* in_sizes, int n_in,
                              void* d_out, int out_size, void* d_ws, size_t ws_size,
                              hipStream_t stream) {
  const float* spatial  = (const float*)d_in[0];
  const float* temporal = (const float*)d_in[1];
  const float* W1_w     = (const float*)d_in[2];
  const float* W1_b     = (const float*)d_in[3];
  const float* W2_w     = (const float*)d_in[4];
  const float* W2_b     = (const float*)d_in[5];
  const int*   ts_mask  = (const int*)d_in[6];
  float* out = (float*)d_out;

  float* ws = (float*)d_ws;
  float* v      = ws;                  // N*H
  float* c      = v  + (size_t)Nd*Hd;  // N
  float* Wc     = c  + Nd;             // H*H
  float* vb     = Wc + Hd*Hd;          // H
  float* u      = vb + Hd;             // H
  float* cconst = u  + Hd;             // 1

  combo_kernel<<<Hd, Hd, 0, stream>>>(W1_w, W1_b, W2_w, W2_b, Wc, vb, u, cconst);
  v_kernel<<<Nd/GB, 256, 0, stream>>>(temporal, Wc, vb, u, cconst, v, c);
  attn_kernel<<<Nd, 256, 0, stream>>>(spatial, ts_mask, v, c, out);
}

// Round 6
// 53.255 us; speedup vs baseline: 1.7909x; 1.2803x over previous
//
#include <hip/hip_runtime.h>

#define Hd 256
#define Ad 64
#define NPSd 48
#define Sd 64
#define Nd (Sd*NPSd)
#define GB 4     // agents per block in v_kernel
#define RPW 12   // rows per wave in attn_kernel (48 rows / 4 waves)

// ---------------------------------------------------------------------------
// Kernel A: combo weights.  Wc[h1][h] = sum_a W2[a][h1]*W1[a][h]
//           vb[h] = sum_a b2[a]*W1[a][h]
//           u[h1] = sum_a W2[a][h1]*b1[a]
//           cconst = b1.b2
__global__ __launch_bounds__(256) void combo_kernel(
    const float* __restrict__ W1_w, const float* __restrict__ W1_b,
    const float* __restrict__ W2_w, const float* __restrict__ W2_b,
    float* __restrict__ Wc, float* __restrict__ vb,
    float* __restrict__ u, float* __restrict__ cconst) {
  int h1 = blockIdx.x;
  int h  = threadIdx.x;
  float acc = 0.f;
#pragma unroll 8
  for (int a = 0; a < Ad; ++a)
    acc += W2_w[a*Hd + h1] * W1_w[a*Hd + h];
  Wc[h1*Hd + h] = acc;
  if (h1 == 0) {
    float uu = 0.f, vbb = 0.f;
    for (int a = 0; a < Ad; ++a) {
      uu  += W2_w[a*Hd + h] * W1_b[a];
      vbb += W2_b[a] * W1_w[a*Hd + h];
    }
    u[h]  = uu;
    vb[h] = vbb;
    if (h == 0) {
      float cc = 0.f;
      for (int a = 0; a < Ad; ++a) cc += W1_b[a] * W2_b[a];
      *cconst = cc;
    }
  }
}

// ---------------------------------------------------------------------------
// Kernel B: v[i][:] = t[i].Wc + vb ;  c[i] = t[i].u + cconst
// GB=4 agents/block -> 768 blocks (3/CU) for latency hiding.
__global__ __launch_bounds__(256) void v_kernel(
    const float* __restrict__ temporal,
    const float* __restrict__ Wc, const float* __restrict__ vb,
    const float* __restrict__ u, const float* __restrict__ cconst,
    float* __restrict__ v, float* __restrict__ c) {
  __shared__ float t_lds[GB*Hd];
  __shared__ float u_lds[Hd];
  __shared__ float vb_lds[Hd];
  int tid  = threadIdx.x;
  int base = blockIdx.x * GB;
  for (int k = tid; k < GB*Hd; k += 256)
    t_lds[k] = temporal[(size_t)base*Hd + k];
  u_lds[tid]  = u[tid];
  vb_lds[tid] = vb[tid];
  __syncthreads();

  float acc[GB];
#pragma unroll
  for (int g = 0; g < GB; ++g) acc[g] = 0.f;
#pragma unroll 8
  for (int h1 = 0; h1 < Hd; ++h1) {
    float wc = Wc[h1*Hd + tid];          // coalesced over tid, L2-hot
#pragma unroll
    for (int g = 0; g < GB; ++g)
      acc[g] += t_lds[g*Hd + h1] * wc;   // LDS broadcast
  }
#pragma unroll
  for (int g = 0; g < GB; ++g)
    v[(size_t)(base+g)*Hd + tid] = acc[g] + vb_lds[tid];

  int wave = tid >> 6, lane = tid & 63;
  float cc0 = *cconst;
  {
    int g = wave;                        // GB==4: one agent per wave
    float p = 0.f;
#pragma unroll
    for (int k = 0; k < Hd/64; ++k)
      p += t_lds[g*Hd + lane + k*64] * u_lds[lane + k*64];
#pragma unroll
    for (int off = 32; off > 0; off >>= 1)
      p += __shfl_down(p, off);
    if (lane == 0) c[base+g] = p + cc0;
  }
}

// ---------------------------------------------------------------------------
// Kernel C: fused score + masked (unstabilized) softmax + aggregation,
// REGISTER-RESIDENT: no spatial LDS staging at all. Each wave loads its 12
// rows as float4 into registers, computes score via shfl_xor butterfly
// (all lanes end with the full dot product), and accumulates its partial
// output o4 += nj*a4 in registers. One barrier + 4 KB LDS cross-wave
// reduction at the end. Occupancy is VGPR-capped (~5-6 blocks/CU) instead
// of LDS-capped (3).
__global__ __launch_bounds__(256) void attn_kernel(
    const float* __restrict__ spatial,
    const int* __restrict__ ts_mask,
    const float* __restrict__ v, const float* __restrict__ c,
    float* __restrict__ out) {
  __shared__ float red[4*Hd];   // [wave][h] partial outputs, 4 KB
  __shared__ float denr[4];

  int row = blockIdx.x;               // 0..N-1
  int s = row / NPSd, i = row - s*NPSd;
  int tid  = threadIdx.x;
  int wave = tid >> 6, lane = tid & 63;

  const float* rowbase = spatial + (size_t)row*NPSd*Hd;

  int ml = lane < NPSd ? lane : NPSd-1;
  int mv = ts_mask[s*NPSd + ml];
  unsigned long long mb = __ballot(mv == 1 && lane < NPSd);
  float ne = (float)__popcll(mb);
  float scale = ne * 0.125f;          // ne / sqrt(A=64)
  bool rowv = (mb >> (unsigned)i) & 1ULL;

  float4 vv = ((const float4*)(v + (size_t)row*Hd))[lane];
  float cr = c[row];

  // load this wave's 12 rows (stride 4) into registers; 12 independent
  // 1 KB-per-wave coalesced loads, all in flight
  float4 rws[RPW];
#pragma unroll
  for (int r = 0; r < RPW; ++r)
    rws[r] = ((const float4*)(rowbase + (size_t)(wave + r*4)*Hd))[lane];

  float4 o4 = make_float4(0.f, 0.f, 0.f, 0.f);
  float den = 0.f;
#pragma unroll
  for (int r = 0; r < RPW; ++r) {
    int j = wave + r*4;
    float4 a4 = rws[r];
    float p = a4.x*vv.x + a4.y*vv.y + a4.z*vv.z + a4.w*vv.w;
    p += __shfl_xor(p, 1);
    p += __shfl_xor(p, 2);
    p += __shfl_xor(p, 4);
    p += __shfl_xor(p, 8);
    p += __shfl_xor(p, 16);
    p += __shfl_xor(p, 32);
    bool valid = rowv && ((mb >> (unsigned)j) & 1ULL) && (j != i);
    float nj = valid ? __expf((p + cr) * scale) : 0.f;
    den += nj;
    o4.x += nj * a4.x;
    o4.y += nj * a4.y;
    o4.z += nj * a4.z;
    o4.w += nj * a4.w;
  }

  // cross-wave reduction: wave w's o4 covers h = lane*4..lane*4+3
  ((float4*)red)[wave*64 + lane] = o4;
  if (lane == 0) denr[wave] = den;
  __syncthreads();

  float o = red[0*Hd + tid] + red[1*Hd + tid] + red[2*Hd + tid] + red[3*Hd + tid];
  float dtot = denr[0] + denr[1] + denr[2] + denr[3];
  out[(size_t)row*Hd + tid] = o * (dtot > 0.f ? 1.f/dtot : 0.f);
}

// ---------------------------------------------------------------------------
extern "C" void kernel_launch(void* const* d_in, const int* in_sizes, int n_in,
                              void* d_out, int out_size, void* d_ws, size_t ws_size,
                              hipStream_t stream) {
  const float* spatial  = (const float*)d_in[0];
  const float* temporal = (const float*)d_in[1];
  const float* W1_w     = (const float*)d_in[2];
  const float* W1_b     = (const float*)d_in[3];
  const float* W2_w     = (const float*)d_in[4];
  const float* W2_b     = (const float*)d_in[5];
  const int*   ts_mask  = (const int*)d_in[6];
  float* out = (float*)d_out;

  float* ws = (float*)d_ws;
  float* v      = ws;                  // N*H
  float* c      = v  + (size_t)Nd*Hd;  // N
  float* Wc     = c  + Nd;             // H*H
  float* vb     = Wc + Hd*Hd;          // H
  float* u      = vb + Hd;             // H
  float* cconst = u  + Hd;             // 1

  combo_kernel<<<Hd, Hd, 0, stream>>>(W1_w, W1_b, W2_w, W2_b, Wc, vb, u, cconst);
  v_kernel<<<Nd/GB, 256, 0, stream>>>(temporal, Wc, vb, u, cconst, v, c);
  attn_kernel<<<Nd, 256, 0, stream>>>(spatial, ts_mask, v, c, out);
}

// Round 7
// 47.717 us; speedup vs baseline: 1.9987x; 1.1161x over previous
//
#include <hip/hip_runtime.h>

#define Hd 256
#define NPSd 48
#define Sd 64
#define Nd (Sd*NPSd)

// LDS-only barrier: no vmcnt drain, so in-flight global loads survive it.
__device__ __forceinline__ void barrier_lds() {
  asm volatile("s_waitcnt lgkmcnt(0)" ::: "memory");
  __builtin_amdgcn_s_barrier();
}

// ---------------------------------------------------------------------------
// Single fused kernel: one block per (scene, agent-row).
//  phase 1: pt = W2 * t[row] + b2        (64-vec; lane-a ownership, 2 shfl)
//  phase 2: v  = W1^T * pt, cr = b1 . pt (coalesced W1 reads, LDS broadcasts)
//  phase 3: scores p_j = sp[j].v, masked unstabilized softmax, aggregation
//           o = sum_j attn_j * sp[j]     (register-resident rows, as R5)
// Spatial rows issued in two 6-row halves; W1 issued before spatial
// (sched_barrier pins order; vmcnt retires in-order so newer-L2-after-older-
// HBM would stall). Barriers after spatial issue are LDS-only.
__global__ __launch_bounds__(256) void fused_kernel(
    const float* __restrict__ spatial,
    const float* __restrict__ temporal,
    const float* __restrict__ W1_w, const float* __restrict__ W1_b,
    const float* __restrict__ W2_w, const float* __restrict__ W2_b,
    const int* __restrict__ ts_mask,
    float* __restrict__ out) {
  __shared__ float t_lds[4*68];   // 4 quarters of t, padded +4 (bank spread)
  __shared__ float pt_lds[64];
  __shared__ float crp[4];
  __shared__ float vred[4*Hd];    // per-wave v partials
  __shared__ float red[4*Hd];     // per-wave output partials
  __shared__ float denr[4];

  int row = blockIdx.x;               // 0..N-1
  int s = row / NPSd, i = row - s*NPSd;
  int tid  = threadIdx.x;
  int wave = tid >> 6, lane = tid & 63;

  // ---- top loads (oldest in vmcnt queue; all small / L2)
  int ml = lane < NPSd ? lane : NPSd-1;
  int mv = ts_mask[s*NPSd + ml];
  int al = (wave<<4) + (lane & 15);   // this lane's a-index
  float b1v = W1_b[al];
  float b2v = W2_b[al];
  // stage t: h = tid, quarter q=h>>6, element k=h&63, padded stride 68
  t_lds[(tid>>6)*68 + (tid&63)] = temporal[(size_t)row*Hd + tid];
  __syncthreads();

  // ---- phase 1: pt[a] = sum_h W2[a][h]*t[h] + b2[a]
  int q = lane >> 4;                  // quarter of h owned by this lane
  const float4* w2p = (const float4*)(W2_w + (size_t)al*Hd + q*64);
  float p = 0.f;
#pragma unroll
  for (int m = 0; m < 16; ++m) {
    float4 wv = w2p[m];
    p += wv.x * t_lds[q*68 + m*4 + 0];
    p += wv.y * t_lds[q*68 + m*4 + 1];
    p += wv.z * t_lds[q*68 + m*4 + 2];
    p += wv.w * t_lds[q*68 + m*4 + 3];
  }
  p += __shfl_xor(p, 16);             // combine quarters
  p += __shfl_xor(p, 32);
  float pfull = p + b2v;              // pt[al], replicated in 4 lanes
  // cr partial: sum over this wave's 16 a's
  float cb = pfull * b1v;
  cb += __shfl_xor(cb, 1);
  cb += __shfl_xor(cb, 2);
  cb += __shfl_xor(cb, 4);
  cb += __shfl_xor(cb, 8);
  if (lane < 16) pt_lds[(wave<<4) + lane] = pfull;
  if (lane == 0) crp[wave] = cb;
  __syncthreads();

  // ---- phase 2: v[h] = sum_a pt[a]*W1[a][h]; wave covers a = wave*16..+15
  float4 w1r[16];
#pragma unroll
  for (int j = 0; j < 16; ++j)
    w1r[j] = ((const float4*)(W1_w + (size_t)((wave<<4)+j)*Hd))[lane];
  __builtin_amdgcn_sched_barrier(0);  // W1 issued before spatial

  const float* rowbase = spatial + (size_t)row*NPSd*Hd;
  float4 rws0[6];
#pragma unroll
  for (int r = 0; r < 6; ++r)
    rws0[r] = ((const float4*)(rowbase + (size_t)(wave + r*4)*Hd))[lane];
  __builtin_amdgcn_sched_barrier(0);  // spatial issued before v-MACs

  float4 v4 = make_float4(0.f, 0.f, 0.f, 0.f);
#pragma unroll
  for (int j = 0; j < 16; ++j) {
    float pj = pt_lds[(wave<<4) + j]; // LDS broadcast
    float4 wv = w1r[j];
    v4.x += pj * wv.x;
    v4.y += pj * wv.y;
    v4.z += pj * wv.z;
    v4.w += pj * wv.w;
  }
  ((float4*)vred)[(wave<<6) + lane] = v4;
  barrier_lds();                      // spatial half-1 stays in flight

  // issue spatial half-2 early (newer than half-1: no wait inversion)
  float4 rws1[6];
#pragma unroll
  for (int r = 0; r < 6; ++r)
    rws1[r] = ((const float4*)(rowbase + (size_t)(wave + (r+6)*4)*Hd))[lane];

  // combine v partials: vv = v[4*lane .. 4*lane+3]
  float4 vv = make_float4(0.f, 0.f, 0.f, 0.f);
#pragma unroll
  for (int w = 0; w < 4; ++w) {
    float4 t4 = ((const float4*)(vred + w*Hd))[lane];
    vv.x += t4.x; vv.y += t4.y; vv.z += t4.z; vv.w += t4.w;
  }
  float cr = crp[0] + crp[1] + crp[2] + crp[3];

  unsigned long long mb = __ballot(mv == 1 && lane < NPSd);
  float ne = (float)__popcll(mb);
  float scale = ne * 0.125f;          // ne / sqrt(A=64)
  bool rowv = (mb >> (unsigned)i) & 1ULL;

  // ---- phase 3: scores + unstabilized softmax + aggregation
  float4 o4 = make_float4(0.f, 0.f, 0.f, 0.f);
  float den = 0.f;

#define SCORE_ROW(A4, J)                                                    \
  {                                                                         \
    float4 a4 = (A4);                                                       \
    int j = (J);                                                            \
    float pp = a4.x*vv.x + a4.y*vv.y + a4.z*vv.z + a4.w*vv.w;               \
    pp += __shfl_xor(pp, 1);                                                \
    pp += __shfl_xor(pp, 2);                                                \
    pp += __shfl_xor(pp, 4);                                                \
    pp += __shfl_xor(pp, 8);                                                \
    pp += __shfl_xor(pp, 16);                                               \
    pp += __shfl_xor(pp, 32);                                               \
    bool valid = rowv && ((mb >> (unsigned)j) & 1ULL) && (j != i);          \
    float nj = valid ? __expf((pp + cr) * scale) : 0.f;                     \
    den += nj;                                                              \
    o4.x += nj * a4.x;                                                      \
    o4.y += nj * a4.y;                                                      \
    o4.z += nj * a4.z;                                                      \
    o4.w += nj * a4.w;                                                      \
  }

#pragma unroll
  for (int r = 0; r < 6; ++r) SCORE_ROW(rws0[r], wave + r*4);
#pragma unroll
  for (int r = 0; r < 6; ++r) SCORE_ROW(rws1[r], wave + (r+6)*4);
#undef SCORE_ROW

  // ---- cross-wave reduction
  ((float4*)red)[(wave<<6) + lane] = o4;
  if (lane == 0) denr[wave] = den;
  barrier_lds();

  float o = red[0*Hd + tid] + red[1*Hd + tid] + red[2*Hd + tid] + red[3*Hd + tid];
  float dtot = denr[0] + denr[1] + denr[2] + denr[3];
  out[(size_t)row*Hd + tid] = o * (dtot > 0.f ? 1.f/dtot : 0.f);
}

// ---------------------------------------------------------------------------
extern "C" void kernel_launch(void* const* d_in, const int* in_sizes, int n_in,
                              void* d_out, int out_size, void* d_ws, size_t ws_size,
                              hipStream_t stream) {
  const float* spatial  = (const float*)d_in[0];
  const float* temporal = (const float*)d_in[1];
  const float* W1_w     = (const float*)d_in[2];
  const float* W1_b     = (const float*)d_in[3];
  const float* W2_w     = (const float*)d_in[4];
  const float* W2_b     = (const float*)d_in[5];
  const int*   ts_mask  = (const int*)d_in[6];
  float* out = (float*)d_out;

  fused_kernel<<<Nd, 256, 0, stream>>>(spatial, temporal, W1_w, W1_b,
                                       W2_w, W2_b, ts_mask, out);
}

// Round 8
// 46.015 us; speedup vs baseline: 2.0727x; 1.0370x over previous
//
#include <hip/hip_runtime.h>

#define Hd 256
#define NPSd 48
#define Sd 64
#define Nd (Sd*NPSd)
#define ROWS 4
#define NB (Nd/ROWS)   // 768 blocks = 3/CU exactly resident

// LDS-only barrier: no vmcnt drain, in-flight global loads survive it.
__device__ __forceinline__ void barrier_lds() {
  asm volatile("s_waitcnt lgkmcnt(0)" ::: "memory");
  __builtin_amdgcn_s_barrier();
}

// ---------------------------------------------------------------------------
// One block = 4 consecutive agent rows of one scene. Phases:
//  1: pt[r] = W2*t[r]+b2 (lane-a ownership, W2 slice reg-cached, reused x4)
//  2: v[r] = W1^T*pt[r] (W1 rows reg-cached once, reused x4), cr[r]=b1.pt[r]
//  3: per row: scores + unstabilized softmax + aggregation, register-resident
//     spatial rows, 2-deep A/B pipeline across rows (next row's 12 loads in
//     flight during current row's compute + reduce barrier).
__global__ __launch_bounds__(256) void fused_kernel(
    const float* __restrict__ spatial,
    const float* __restrict__ temporal,
    const float* __restrict__ W1_w, const float* __restrict__ W1_b,
    const float* __restrict__ W2_w, const float* __restrict__ W2_b,
    const int* __restrict__ ts_mask,
    float* __restrict__ out) {
  __shared__ float t_lds[ROWS][4][72];  // [row][h-quarter][64+pad8] (16B-mult)
  __shared__ float pt_lds[ROWS][64];
  __shared__ float crp[4][ROWS];
  __shared__ float vred[ROWS][4][Hd];   // 16 KB v partials
  __shared__ float vvL[ROWS][Hd];       // 4 KB combined v
  __shared__ float red[2][4][Hd];       // 8 KB out partials, row-parity dbuf
  __shared__ float denr[2][4];

  int blk = blockIdx.x;
  int s    = blk / (NPSd/ROWS);
  int quad = blk % (NPSd/ROWS);
  int i0   = quad*ROWS;                 // first in-scene row index
  int row0 = s*NPSd + i0;               // first global row

  int tid = threadIdx.x;
  int wave = tid >> 6, lane = tid & 63;

  // ---- mask (same for all 4 rows; scene-wide)
  int ml = lane < NPSd ? lane : NPSd-1;
  int mv = ts_mask[s*NPSd + ml];
  unsigned long long mb = __ballot(mv == 1 && lane < NPSd);
  float ne = (float)__popcll(mb);
  float scale = ne * 0.125f;            // ne / sqrt(A=64)

  int al = (wave<<4) + (lane & 15);     // this lane's a-index
  int q  = lane >> 4;                   // h-quarter owned
  float b1v = W1_b[al];
  float b2v = W2_b[al];

  // ---- stage t for 4 rows: thread covers (row = tid>>6, 4 h's)
  {
    int r = tid >> 6, h4 = (tid & 63) << 2;
    float4 tv = *(const float4*)(temporal + (size_t)(row0 + r)*Hd + h4);
    *(float4*)&t_lds[r][h4 >> 6][h4 & 63] = tv;
  }

  // ---- W2 slice into regs (reused for all 4 rows)
  float4 w2r[16];
#pragma unroll
  for (int m = 0; m < 16; ++m)
    w2r[m] = *(const float4*)(W2_w + (size_t)al*Hd + q*64 + m*4);

  __syncthreads();                      // t_lds ready

  // ---- phase 1: pt[r][al] + cr partials
#pragma unroll
  for (int r = 0; r < ROWS; ++r) {
    float p = 0.f;
#pragma unroll
    for (int m = 0; m < 16; ++m) {
      float4 wv = w2r[m];
      p += wv.x * t_lds[r][q][m*4+0];
      p += wv.y * t_lds[r][q][m*4+1];
      p += wv.z * t_lds[r][q][m*4+2];
      p += wv.w * t_lds[r][q][m*4+3];
    }
    p += __shfl_xor(p, 16);             // combine h-quarters
    p += __shfl_xor(p, 32);
    float pfull = p + b2v;              // pt[al] (4 replicas)
    float cb = pfull * b1v;
    cb += __shfl_xor(cb, 1);
    cb += __shfl_xor(cb, 2);
    cb += __shfl_xor(cb, 4);
    cb += __shfl_xor(cb, 8);            // sum over this wave's 16 a's
    if (lane < 16) pt_lds[r][(wave<<4) + lane] = pfull;
    if (lane == 0) crp[wave][r] = cb;
  }
  barrier_lds();

  // ---- phase 2: W1 rows reg-cached, then row0 spatial issued, then v MACs
  float4 w1r[16];
#pragma unroll
  for (int j = 0; j < 16; ++j)
    w1r[j] = *(const float4*)(W1_w + (size_t)((wave<<4)+j)*Hd + (lane<<2));
  __builtin_amdgcn_sched_barrier(0);    // W1 issued before spatial

  float4 A[12], B[12];
#pragma unroll
  for (int rr = 0; rr < 12; ++rr)
    A[rr] = *(const float4*)(spatial +
              ((size_t)(row0+0)*NPSd + (wave + rr*4))*Hd + (lane<<2));
  __builtin_amdgcn_sched_barrier(0);    // spatial(row0) issued before v MACs

#pragma unroll
  for (int r = 0; r < ROWS; ++r) {
    float4 v4 = make_float4(0.f,0.f,0.f,0.f);
#pragma unroll
    for (int j = 0; j < 16; ++j) {
      float pj = pt_lds[r][(wave<<4)+j];   // LDS broadcast
      float4 wv = w1r[j];
      v4.x += pj*wv.x; v4.y += pj*wv.y; v4.z += pj*wv.z; v4.w += pj*wv.w;
    }
    *(float4*)&vred[r][wave][lane<<2] = v4;
  }
  barrier_lds();

  // combine v partials: thread tid owns h=tid for all rows
#pragma unroll
  for (int r = 0; r < ROWS; ++r)
    vvL[r][tid] = vred[r][0][tid] + vred[r][1][tid]
                + vred[r][2][tid] + vred[r][3][tid];
  barrier_lds();

  // ---- phase 3: pipelined rows
#define ISSUE(DST, R)                                                       \
  { _Pragma("unroll")                                                       \
    for (int rr = 0; rr < 12; ++rr)                                         \
      DST[rr] = *(const float4*)(spatial +                                  \
                 ((size_t)(row0+(R))*NPSd + (wave + rr*4))*Hd + (lane<<2)); \
    __builtin_amdgcn_sched_barrier(0); }

#define DO_ROW(CUR, R)                                                      \
  { int irow = i0 + (R);                                                    \
    bool rowv = (mb >> (unsigned)irow) & 1ULL;                              \
    float4 vv = *(const float4*)&vvL[R][lane<<2];                           \
    float cr = crp[0][R] + crp[1][R] + crp[2][R] + crp[3][R];               \
    float4 o4 = make_float4(0.f,0.f,0.f,0.f);                               \
    float den = 0.f;                                                        \
    _Pragma("unroll")                                                       \
    for (int rr = 0; rr < 12; ++rr) {                                       \
      int j = wave + rr*4;                                                  \
      float4 a4 = CUR[rr];                                                  \
      float pp = a4.x*vv.x + a4.y*vv.y + a4.z*vv.z + a4.w*vv.w;             \
      pp += __shfl_xor(pp, 1);                                              \
      pp += __shfl_xor(pp, 2);                                              \
      pp += __shfl_xor(pp, 4);                                              \
      pp += __shfl_xor(pp, 8);                                              \
      pp += __shfl_xor(pp, 16);                                             \
      pp += __shfl_xor(pp, 32);                                             \
      bool valid = rowv && ((mb >> (unsigned)j) & 1ULL) && (j != irow);     \
      float nj = valid ? __expf((pp + cr) * scale) : 0.f;                   \
      den += nj;                                                            \
      o4.x += nj*a4.x; o4.y += nj*a4.y; o4.z += nj*a4.z; o4.w += nj*a4.w;   \
    }                                                                       \
    *(float4*)&red[(R)&1][wave][lane<<2] = o4;                              \
    if (lane == 0) denr[(R)&1][wave] = den;                                 \
    barrier_lds();                                                          \
    float o = red[(R)&1][0][tid] + red[(R)&1][1][tid]                       \
            + red[(R)&1][2][tid] + red[(R)&1][3][tid];                      \
    float dt = denr[(R)&1][0] + denr[(R)&1][1]                              \
             + denr[(R)&1][2] + denr[(R)&1][3];                             \
    out[(size_t)(row0+(R))*Hd + tid] = o * (dt > 0.f ? 1.f/dt : 0.f); }

  ISSUE(B, 1);
  DO_ROW(A, 0);
  ISSUE(A, 2);
  DO_ROW(B, 1);
  ISSUE(B, 3);
  DO_ROW(A, 2);
  DO_ROW(B, 3);

#undef ISSUE
#undef DO_ROW
}

// ---------------------------------------------------------------------------
extern "C" void kernel_launch(void* const* d_in, const int* in_sizes, int n_in,
                              void* d_out, int out_size, void* d_ws, size_t ws_size,
                              hipStream_t stream) {
  const float* spatial  = (const float*)d_in[0];
  const float* temporal = (const float*)d_in[1];
  const float* W1_w     = (const float*)d_in[2];
  const float* W1_b     = (const float*)d_in[3];
  const float* W2_w     = (const float*)d_in[4];
  const float* W2_b     = (const float*)d_in[5];
  const int*   ts_mask  = (const int*)d_in[6];
  float* out = (float*)d_out;

  fused_kernel<<<NB, 256, 0, stream>>>(spatial, temporal, W1_w, W1_b,
                                       W2_w, W2_b, ts_mask, out);
}